// Round 1
// baseline (244.020 us; speedup 1.0000x reference)
//
#include <hip/hip_runtime.h>
#include <math.h>

// SOFT top-k/bottom-k via Sinkhorn between n=4096 scores (uniform marginal)
// and m=3 anchors {0, 0.5, 1} with nu = [k/n, (n-2k)/n, k/n], eps=0.1,
// 200 iterations.
//
// Restructured iteration (algebraically identical to reference):
//   E_ij = exp(-(x_i - a_j)^2 / eps)            (iteration-invariant)
//   d_i  = sum_j E_ij * exp(v_j)                (row/ u-update)
//   r_i  = 1/d_i            => exp(u_i) = r_i / n
//   A_j  = sum_i E_ij * r_i                     (column sums)
//   v_j  = log(nu_j * n) - log(A_j)
// Output: n*(Gamma_2 - Gamma_0) = r_i * (E_i2*ev2 - E_i0*ev0)
// (r from last iteration = f(v_199); ev = exp(v_final) — matches scan order.)

constexpr int N_ELEM  = 4096;
constexpr int THREADS = 256;
constexpr int EPT     = N_ELEM / THREADS;  // 16 elements per thread
constexpr int KTOP    = 512;
constexpr int MAXIT   = 200;

__global__ __launch_bounds__(THREADS)
void SoftTopKBottomK_kernel(const float* __restrict__ scores,
                            float* __restrict__ out)
{
    const int row  = blockIdx.x;
    const int t    = threadIdx.x;
    const int lane = t & 63;
    const int wave = t >> 6;

    const float4* srow = (const float4*)(scores + (size_t)row * N_ELEM);
    float4*       orow = (float4*)(out + (size_t)row * N_ELEM);

    // ---- load + per-row min/max ------------------------------------------
    float4 xs[4];
    float lmin = INFINITY, lmax = -INFINITY;
#pragma unroll
    for (int c = 0; c < 4; ++c) {
        xs[c] = srow[c * THREADS + t];           // coalesced 16B/lane
        lmin = fminf(lmin, fminf(fminf(xs[c].x, xs[c].y), fminf(xs[c].z, xs[c].w)));
        lmax = fmaxf(lmax, fmaxf(fmaxf(xs[c].x, xs[c].y), fmaxf(xs[c].z, xs[c].w)));
    }
#pragma unroll
    for (int off = 32; off > 0; off >>= 1) {
        lmin = fminf(lmin, __shfl_xor(lmin, off, 64));
        lmax = fmaxf(lmax, __shfl_xor(lmax, off, 64));
    }
    __shared__ float s_mm[4][2];
    if (lane == 0) { s_mm[wave][0] = lmin; s_mm[wave][1] = lmax; }
    __syncthreads();
    const float smin = fminf(fminf(s_mm[0][0], s_mm[1][0]), fminf(s_mm[2][0], s_mm[3][0]));
    const float smax = fmaxf(fmaxf(s_mm[0][1], s_mm[1][1]), fmaxf(s_mm[2][1], s_mm[3][1]));
    const float inv  = 1.0f / (smax - smin + 1e-12f);

    // ---- precompute Gibbs kernel E (iteration-invariant) -----------------
    float E0[EPT], E1[EPT], E2[EPT];
    const float inv_eps = 1.0f / 0.1f;
#pragma unroll
    for (int c = 0; c < 4; ++c) {
        const float xv[4] = {xs[c].x, xs[c].y, xs[c].z, xs[c].w};
#pragma unroll
        for (int q = 0; q < 4; ++q) {
            const int e = c * 4 + q;
            const float x  = (xv[q] - smin) * inv;
            const float d0 = x;
            const float d1 = x - 0.5f;
            const float d2 = x - 1.0f;
            E0[e] = __expf(-inv_eps * d0 * d0);
            E1[e] = __expf(-inv_eps * d1 * d1);
            E2[e] = __expf(-inv_eps * d2 * d2);
        }
    }

    // v-update constants: log(nu_j * n)
    const float c0 = logf((float)KTOP);                 // log 512
    const float c1 = logf((float)(N_ELEM - 2 * KTOP));  // log 3072
    const float c2 = c0;

    float ev0 = 1.0f, ev1 = 1.0f, ev2 = 1.0f;           // exp(v), v starts 0
    float r[EPT];

    __shared__ __align__(16) float s_part[2][16];       // double-buffered partials

    for (int it = 0; it < MAXIT; ++it) {
        float A0 = 0.f, A1 = 0.f, A2 = 0.f;
#pragma unroll
        for (int e = 0; e < EPT; ++e) {
            const float d  = E0[e] * ev0 + E1[e] * ev1 + E2[e] * ev2;
            const float ri = __builtin_amdgcn_rcpf(d);  // v_rcp_f32, ~1 ulp
            r[e] = ri;
            A0 += E0[e] * ri;
            A1 += E1[e] * ri;
            A2 += E2[e] * ri;
        }
        // 64-lane butterfly: every lane ends with the wave sum
#pragma unroll
        for (int off = 32; off > 0; off >>= 1) {
            A0 += __shfl_xor(A0, off, 64);
            A1 += __shfl_xor(A1, off, 64);
            A2 += __shfl_xor(A2, off, 64);
        }
        float* p = &s_part[it & 1][0];
        if (lane == 0) {
            p[0 + wave]  = A0;   // [anchor][wave] layout
            p[4 + wave]  = A1;
            p[8 + wave]  = A2;
        }
        __syncthreads();         // single barrier/iter thanks to double buffer
        const float4 q0 = *(const float4*)&p[0];
        const float4 q1 = *(const float4*)&p[4];
        const float4 q2 = *(const float4*)&p[8];
        A0 = (q0.x + q0.y) + (q0.z + q0.w);
        A1 = (q1.x + q1.y) + (q1.z + q1.w);
        A2 = (q2.x + q2.y) + (q2.z + q2.w);
        // v_j = log(nu_j*n) - log(A_j); keep exp(v_j) for next iteration
        ev0 = __expf(c0 - __logf(A0));
        ev1 = __expf(c1 - __logf(A1));
        ev2 = __expf(c2 - __logf(A2));
    }

    // ---- epilogue: out = r_i * (E2*ev2 - E0*ev0) -------------------------
#pragma unroll
    for (int c = 0; c < 4; ++c) {
        float4 o;
        float* op = &o.x;
#pragma unroll
        for (int q = 0; q < 4; ++q) {
            const int e = c * 4 + q;
            op[q] = r[e] * (E2[e] * ev2 - E0[e] * ev0);
        }
        orow[c * THREADS + t] = o;
    }
}

extern "C" void kernel_launch(void* const* d_in, const int* in_sizes, int n_in,
                              void* d_out, int out_size, void* d_ws, size_t ws_size,
                              hipStream_t stream)
{
    const float* scores = (const float*)d_in[0];
    float* out = (float*)d_out;
    const int rows = in_sizes[0] / N_ELEM;   // 512
    SoftTopKBottomK_kernel<<<rows, THREADS, 0, stream>>>(scores, out);
}

// Round 2
// 73.704 us; speedup vs baseline: 3.3108x; 3.3108x over previous
//
#include <hip/hip_runtime.h>
#include <math.h>

// SOFT top-k/bottom-k (Sinkhorn OT, n=4096 scores vs m=3 anchors {0,.5,1},
// eps=0.1, <=200 iters, nu = [k, n-2k, k]/n with k=512).
//
// Algebra (divide everything by E1 = exp(-10(x-.5)^2)):
//   s  = exp(10x-5), rs = 1/s, K = exp(-2.5)
//   E0 = E1*K*rs, E2 = E1*K*s
//   Track e0 := K*exp(v0), e1 := exp(v1), e2 := K*exp(v2). Then
//     g_i = e1 + rs_i*e0 + s_i*e2          (d_i / E1_i)
//     p_i = 1/g_i                          (E1_i * r_i)
//     S0 = sum rs_i*p_i, S1 = sum p_i, S2 = sum s_i*p_i
//     e0 <- 512/S0, e1 <- 3072/S1, e2 <- 512/S2     (exact v-update, no exp/log)
//   Output: n*(Gamma2 - Gamma0) = p_i*(s_i*e2 - rs_i*e0), with p from the
//   PREVIOUS potentials (u_T = f(v_{T-1})) matching the reference scan phase.
//
// Early exit: at the fp32 fixed point the update is exactly stationary;
// once relative change < 3e-6 the remaining iterations are numerical no-ops
// (residual drift ~1e-4 << 1.9e-2 threshold). Branch is block-uniform.

constexpr int N_ELEM  = 4096;
constexpr int THREADS = 512;                 // 8 waves -> 16 waves/CU (50% occ)
constexpr int EPT     = N_ELEM / THREADS;    // 8 elements per thread
constexpr int NWAVE   = THREADS / 64;        // 8
constexpr int MAXIT   = 200;

__global__ __launch_bounds__(THREADS)
void SoftTopKBottomK_kernel(const float* __restrict__ scores,
                            float* __restrict__ out)
{
    const int row  = blockIdx.x;
    const int t    = threadIdx.x;
    const int lane = t & 63;
    const int wave = t >> 6;

    const float4* srow = (const float4*)(scores + (size_t)row * N_ELEM);
    float4*       orow = (float4*)(out + (size_t)row * N_ELEM);

    // ---- load + per-row min/max ------------------------------------------
    float4 xs[2];
    float lmin = INFINITY, lmax = -INFINITY;
#pragma unroll
    for (int c = 0; c < 2; ++c) {
        xs[c] = srow[c * THREADS + t];       // coalesced 16B/lane
        lmin = fminf(lmin, fminf(fminf(xs[c].x, xs[c].y), fminf(xs[c].z, xs[c].w)));
        lmax = fmaxf(lmax, fmaxf(fmaxf(xs[c].x, xs[c].y), fmaxf(xs[c].z, xs[c].w)));
    }
#pragma unroll
    for (int off = 32; off > 0; off >>= 1) {
        lmin = fminf(lmin, __shfl_xor(lmin, off, 64));
        lmax = fmaxf(lmax, __shfl_xor(lmax, off, 64));
    }
    __shared__ float s_mm[NWAVE][2];
    if (lane == 0) { s_mm[wave][0] = lmin; s_mm[wave][1] = lmax; }
    __syncthreads();
    float smin = s_mm[0][0], smax = s_mm[0][1];
#pragma unroll
    for (int w = 1; w < NWAVE; ++w) {
        smin = fminf(smin, s_mm[w][0]);
        smax = fmaxf(smax, s_mm[w][1]);
    }
    const float inv = 1.0f / (smax - smin + 1e-12f);

    // ---- precompute s = exp(10x-5), rs = exp(5-10x) ----------------------
    float s[EPT], rs[EPT];
#pragma unroll
    for (int c = 0; c < 2; ++c) {
        const float xv[4] = {xs[c].x, xs[c].y, xs[c].z, xs[c].w};
#pragma unroll
        for (int q = 0; q < 4; ++q) {
            const int e = c * 4 + q;
            const float x = (xv[q] - smin) * inv;
            const float z = 10.0f * x - 5.0f;
            s[e]  = __expf(z);
            rs[e] = __expf(-z);
        }
    }

    const float Kc = 0.0820849986238988f;    // exp(-2.5)
    float e0 = Kc, e1 = 1.0f, e2 = Kc;       // v = 0 initially
    float e0p = e0, e1p = e1, e2p = e2;      // previous potentials (v_{T-1})

    __shared__ __align__(16) float s_part[2][3 * NWAVE];   // double-buffered

    for (int it = 0; it < MAXIT; ++it) {
        float S0 = 0.f, S1 = 0.f, S2 = 0.f;
#pragma unroll
        for (int e = 0; e < EPT; ++e) {
            const float g = fmaf(rs[e], e0, fmaf(s[e], e2, e1));
            const float p = __builtin_amdgcn_rcpf(g);
            S1 += p;
            S0 = fmaf(rs[e], p, S0);
            S2 = fmaf(s[e],  p, S2);
        }
        // 64-lane butterfly (3 independent chains for ILP)
#pragma unroll
        for (int off = 32; off > 0; off >>= 1) {
            S0 += __shfl_xor(S0, off, 64);
            S1 += __shfl_xor(S1, off, 64);
            S2 += __shfl_xor(S2, off, 64);
        }
        float* pb = &s_part[it & 1][0];
        if (lane == 0) {
            pb[0 * NWAVE + wave] = S0;
            pb[1 * NWAVE + wave] = S1;
            pb[2 * NWAVE + wave] = S2;
        }
        __syncthreads();   // single barrier/iter (double-buffered partials)
        const float4 a0 = *(const float4*)&pb[0];
        const float4 b0 = *(const float4*)&pb[4];
        const float4 a1 = *(const float4*)&pb[8];
        const float4 b1 = *(const float4*)&pb[12];
        const float4 a2 = *(const float4*)&pb[16];
        const float4 b2 = *(const float4*)&pb[20];
        S0 = ((a0.x + b0.x) + (a0.y + b0.y)) + ((a0.z + b0.z) + (a0.w + b0.w));
        S1 = ((a1.x + b1.x) + (a1.y + b1.y)) + ((a1.z + b1.z) + (a1.w + b1.w));
        S2 = ((a2.x + b2.x) + (a2.y + b2.y)) + ((a2.z + b2.z) + (a2.w + b2.w));

        e0p = e0; e1p = e1; e2p = e2;
        e0 = 512.0f  * __builtin_amdgcn_rcpf(S0);
        e1 = 3072.0f * __builtin_amdgcn_rcpf(S1);
        e2 = 512.0f  * __builtin_amdgcn_rcpf(S2);

        // block-uniform convergence test (identical values in every thread)
        const float d0 = fabsf(e0 - e0p) - 3e-6f * e0;
        const float d1 = fabsf(e1 - e1p) - 3e-6f * e1;
        const float d2 = fabsf(e2 - e2p) - 3e-6f * e2;
        if (fmaxf(fmaxf(d0, d1), d2) <= 0.0f) break;
    }

    // ---- epilogue: p from PREVIOUS potentials (u_T), ev from final -------
#pragma unroll
    for (int c = 0; c < 2; ++c) {
        float4 o;
        float* op = &o.x;
#pragma unroll
        for (int q = 0; q < 4; ++q) {
            const int e = c * 4 + q;
            const float g = fmaf(rs[e], e0p, fmaf(s[e], e2p, e1p));
            const float p = __builtin_amdgcn_rcpf(g);
            op[q] = p * (s[e] * e2 - rs[e] * e0);
        }
        orow[c * THREADS + t] = o;
    }
}

extern "C" void kernel_launch(void* const* d_in, const int* in_sizes, int n_in,
                              void* d_out, int out_size, void* d_ws, size_t ws_size,
                              hipStream_t stream)
{
    const float* scores = (const float*)d_in[0];
    float* out = (float*)d_out;
    const int rows = in_sizes[0] / N_ELEM;   // 512
    SoftTopKBottomK_kernel<<<rows, THREADS, 0, stream>>>(scores, out);
}